// Round 1
// baseline (38.570 us; speedup 1.0000x reference)
//
#include <hip/hip_runtime.h>

// Problem dims (fixed by setup_inputs)
constexpr int B = 2, C = 32, H = 96, W = 160, D = 32;
constexpr int HW = H * W;            // 15360
constexpr int NP = B * H * W;        // 30720 pixels
constexpr float EPS = 1e-12f;

// ---------------------------------------------------------------------------
// Stage 1: per-pixel channel reductions.
//   s [b,d,h,w] = sum_c q[b,c,h,w] * k[b,c,h,w,d]
//   nk[b,d,h,w] = sum_c k[b,c,h,w,d]^2
//   nq[b,h,w]   = sum_c q[b,c,h,w]^2
// 8 lanes per pixel; lane owns d = dg*4 .. dg*4+3 (float4 loads of k).
// A wave covers 8 consecutive pixels -> 8 * 128B = 1KB contiguous per c-step.
// ---------------------------------------------------------------------------
__global__ __launch_bounds__(256) void dav_stage1(
    const float* __restrict__ q, const float* __restrict__ k,
    float* __restrict__ s, float* __restrict__ nk, float* __restrict__ nq) {
  int gt = blockIdx.x * 256 + threadIdx.x;
  int pixel = gt >> 3;   // pixel index in [0, NP)
  int dg = gt & 7;       // d-group
  if (pixel >= NP) return;
  int b  = pixel / HW;
  int hw = pixel - b * HW;

  const float* kbase = k + ((size_t)b * C * HW + hw) * D + dg * 4;
  const float* qbase = q + (size_t)b * C * HW + hw;

  float4 s4 = make_float4(0.f, 0.f, 0.f, 0.f);
  float4 n4 = make_float4(0.f, 0.f, 0.f, 0.f);
  float  nqv = 0.f;

#pragma unroll
  for (int c = 0; c < C; ++c) {
    float4 k4 = *reinterpret_cast<const float4*>(kbase + (size_t)c * HW * D);
    float  qc = qbase[(size_t)c * HW];
    s4.x = fmaf(qc, k4.x, s4.x);
    s4.y = fmaf(qc, k4.y, s4.y);
    s4.z = fmaf(qc, k4.z, s4.z);
    s4.w = fmaf(qc, k4.w, s4.w);
    n4.x = fmaf(k4.x, k4.x, n4.x);
    n4.y = fmaf(k4.y, k4.y, n4.y);
    n4.z = fmaf(k4.z, k4.z, n4.z);
    n4.w = fmaf(k4.w, k4.w, n4.w);
    nqv  = fmaf(qc, qc, nqv);
  }

  // Planar (B, D, H, W) stores so stage 2 reads/writes are w-coalesced.
  int d0 = dg * 4;
  size_t obase = ((size_t)b * D + d0) * HW + hw;
  s[obase]          = s4.x;
  s[obase + HW]     = s4.y;
  s[obase + 2 * HW] = s4.z;
  s[obase + 3 * HW] = s4.w;
  nk[obase]          = n4.x;
  nk[obase + HW]     = n4.y;
  nk[obase + 2 * HW] = n4.z;
  nk[obase + 3 * HW] = n4.w;
  if (dg == 0) nq[pixel] = nqv;
}

// ---------------------------------------------------------------------------
// Stage 2: 3x3 zero-padded box sums + normalize + write (B,D,H,W).
// One thread per output element; w innermost -> coalesced.
// s/nk total ~8MB -> box re-reads served by L2/L3.
// ---------------------------------------------------------------------------
__global__ __launch_bounds__(256) void dav_stage2(
    const float* __restrict__ s, const float* __restrict__ nk,
    const float* __restrict__ nq, float* __restrict__ out) {
  int idx = blockIdx.x * 256 + threadIdx.x;
  if (idx >= B * D * HW) return;
  int w  = idx % W;
  int h  = (idx / W) % H;
  int bd = idx / HW;        // b*D + d
  int b  = bd / D;

  const float* srow = s  + (size_t)bd * HW;
  const float* nrow = nk + (size_t)bd * HW;
  const float* qrow = nq + (size_t)b * HW;

  float dot = 0.f, k2 = 0.f, q2 = 0.f;
#pragma unroll
  for (int dy = -1; dy <= 1; ++dy) {
    int hh = h + dy;
    if (hh < 0 || hh >= H) continue;
#pragma unroll
    for (int dx = -1; dx <= 1; ++dx) {
      int ww = w + dx;
      if (ww < 0 || ww >= W) continue;
      int off = hh * W + ww;
      dot += srow[off];
      k2  += nrow[off];
      q2  += qrow[off];
    }
  }
  float dq = fmaxf(sqrtf(q2), EPS);
  float dk = fmaxf(sqrtf(k2), EPS);
  out[idx] = dot / (dq * dk);
}

extern "C" void kernel_launch(void* const* d_in, const int* in_sizes, int n_in,
                              void* d_out, int out_size, void* d_ws, size_t ws_size,
                              hipStream_t stream) {
  const float* q = (const float*)d_in[0];               // (B,C,H,W)
  const float* k = (const float*)d_in[1];               // (B,C,H,W,D)
  float* out = (float*)d_out;                           // (B,D,H,W)

  // Workspace layout: s | nk | nq  (all fp32)
  float* s  = (float*)d_ws;                 // NP*D
  float* nk = s + (size_t)NP * D;           // NP*D
  float* nq = nk + (size_t)NP * D;          // NP
  // total = (2*NP*D + NP)*4 B ~= 8 MB

  {
    int threads = NP * 8;                   // 8 lanes per pixel
    int blocks = (threads + 255) / 256;     // 960
    dav_stage1<<<blocks, 256, 0, stream>>>(q, k, s, nk, nq);
  }
  {
    int n = B * D * HW;                     // 983040
    int blocks = (n + 255) / 256;           // 3840
    dav_stage2<<<blocks, 256, 0, stream>>>(s, nk, nq, out);
  }
}

// Round 2
// 38.032 us; speedup vs baseline: 1.0142x; 1.0142x over previous
//
#include <hip/hip_runtime.h>

// Problem dims (fixed by setup_inputs)
constexpr int B = 2, C = 32, H = 96, W = 160, D = 32;
constexpr int HW = H * W;            // 15360
constexpr int NP = B * H * W;        // 30720 pixels
constexpr int WG = W / 4;            // 40 four-wide output groups per row
constexpr float EPS = 1e-12f;

// ---------------------------------------------------------------------------
// Stage 1: per-pixel channel reductions.
//   sn[(b*D+d)*HW + hw] = { sum_c q*k , sum_c k*k }   (interleaved float2)
//   nq[b*HW + hw]       = sum_c q*q
// 8 lanes per pixel; lane owns d = dg*4 .. dg*4+3 (float4 loads of k).
// A wave covers 8 consecutive pixels -> 1KB contiguous per c-step over the
// dominant 126 MB tensor.
// ---------------------------------------------------------------------------
__global__ __launch_bounds__(256) void dav_stage1(
    const float* __restrict__ q, const float* __restrict__ k,
    float2* __restrict__ sn, float* __restrict__ nq) {
  int gt = blockIdx.x * 256 + threadIdx.x;
  int pixel = gt >> 3;   // pixel index in [0, NP)
  int dg = gt & 7;       // d-group
  if (pixel >= NP) return;
  int b  = pixel / HW;
  int hw = pixel - b * HW;

  const float* kbase = k + ((size_t)(b * C) * HW + hw) * D + dg * 4;
  const float* qbase = q + (size_t)(b * C) * HW + hw;

  float4 s4 = make_float4(0.f, 0.f, 0.f, 0.f);
  float4 n4 = make_float4(0.f, 0.f, 0.f, 0.f);
  float  nqv = 0.f;

#pragma unroll
  for (int c = 0; c < C; ++c) {
    float4 k4 = *reinterpret_cast<const float4*>(kbase + (size_t)c * HW * D);
    float  qc = qbase[(size_t)c * HW];
    s4.x = fmaf(qc, k4.x, s4.x);
    s4.y = fmaf(qc, k4.y, s4.y);
    s4.z = fmaf(qc, k4.z, s4.z);
    s4.w = fmaf(qc, k4.w, s4.w);
    n4.x = fmaf(k4.x, k4.x, n4.x);
    n4.y = fmaf(k4.y, k4.y, n4.y);
    n4.z = fmaf(k4.z, k4.z, n4.z);
    n4.w = fmaf(k4.w, k4.w, n4.w);
    nqv  = fmaf(qc, qc, nqv);
  }

  size_t obase = ((size_t)(b * D + dg * 4)) * HW + hw;  // planar (B,D,H,W)
  sn[obase]          = make_float2(s4.x, n4.x);
  sn[obase + HW]     = make_float2(s4.y, n4.y);
  sn[obase + 2 * HW] = make_float2(s4.z, n4.z);
  sn[obase + 3 * HW] = make_float2(s4.w, n4.w);
  if (dg == 0) nq[pixel] = nqv;
}

// ---------------------------------------------------------------------------
// Stage 1.5: rq[p] = 1 / max(sqrt(3x3 box of nq), EPS). One thread per pixel.
// Removes the 9-load q2 box recompute from all 32 d-planes in stage 2.
// ---------------------------------------------------------------------------
__global__ __launch_bounds__(256) void dav_nqbox(
    const float* __restrict__ nq, float* __restrict__ rq) {
  int p = blockIdx.x * 256 + threadIdx.x;
  if (p >= NP) return;
  int w = p % W;
  int h = (p / W) % H;
  int b = p / HW;
  const float* base = nq + (size_t)b * HW;
  float acc = 0.f;
#pragma unroll
  for (int dy = -1; dy <= 1; ++dy) {
    int hh = h + dy;
    if (hh < 0 || hh >= H) continue;
#pragma unroll
    for (int dx = -1; dx <= 1; ++dx) {
      int ww = w + dx;
      if (ww < 0 || ww >= W) continue;
      acc += base[hh * W + ww];
    }
  }
  rq[p] = 1.f / fmaxf(sqrtf(acc), EPS);
}

// ---------------------------------------------------------------------------
// Stage 2: 3x3 box sums + normalize. 4 outputs (along w) per thread via
// shared column sums: 6 col-sums serve 4 overlapping windows.
// 18 float2 + 1 float4 loads per 4 outputs; float4 output store.
// ---------------------------------------------------------------------------
__global__ __launch_bounds__(256) void dav_stage2(
    const float2* __restrict__ sn, const float* __restrict__ rq,
    float* __restrict__ out) {
  int idx = blockIdx.x * 256 + threadIdx.x;
  if (idx >= B * D * H * WG) return;
  int g  = idx % WG;
  int h  = (idx / WG) % H;
  int bd = idx / (WG * H);   // b*D + d
  int b  = bd / D;
  int w0 = g * 4;

  float csS[6] = {0.f, 0.f, 0.f, 0.f, 0.f, 0.f};
  float csN[6] = {0.f, 0.f, 0.f, 0.f, 0.f, 0.f};
  const float2* plane = sn + (size_t)bd * HW;
#pragma unroll
  for (int r = -1; r <= 1; ++r) {
    int hh = h + r;
    if (hh < 0 || hh >= H) continue;
    const float2* row = plane + hh * W;
#pragma unroll
    for (int i = 0; i < 6; ++i) {
      int c = w0 - 1 + i;
      if (c >= 0 && c < W) {
        float2 v = row[c];
        csS[i] += v.x;
        csN[i] += v.y;
      }
    }
  }

  float4 rq4 = *reinterpret_cast<const float4*>(rq + (size_t)b * HW + h * W + w0);
  const float* rqa = &rq4.x;
  float o[4];
#pragma unroll
  for (int i = 0; i < 4; ++i) {
    float dot = csS[i] + csS[i + 1] + csS[i + 2];
    float k2  = csN[i] + csN[i + 1] + csN[i + 2];
    float dk  = fmaxf(sqrtf(k2), EPS);
    o[i] = dot * rqa[i] / dk;
  }
  *reinterpret_cast<float4*>(out + (size_t)bd * HW + h * W + w0) =
      make_float4(o[0], o[1], o[2], o[3]);
}

extern "C" void kernel_launch(void* const* d_in, const int* in_sizes, int n_in,
                              void* d_out, int out_size, void* d_ws, size_t ws_size,
                              hipStream_t stream) {
  const float* q = (const float*)d_in[0];               // (B,C,H,W)
  const float* k = (const float*)d_in[1];               // (B,C,H,W,D)
  float* out = (float*)d_out;                           // (B,D,H,W)

  // Workspace layout: sn (float2, NP*D) | nq (float, NP) | rq (float, NP)
  float2* sn = (float2*)d_ws;                           // 7.86 MB
  float*  nq = (float*)(sn + (size_t)NP * D);           // 0.12 MB
  float*  rq = nq + NP;                                 // 0.12 MB

  {
    int threads = NP * 8;                   // 8 lanes per pixel
    int blocks = (threads + 255) / 256;     // 960
    dav_stage1<<<blocks, 256, 0, stream>>>(q, k, sn, nq);
  }
  {
    int blocks = (NP + 255) / 256;          // 120
    dav_nqbox<<<blocks, 256, 0, stream>>>(nq, rq);
  }
  {
    int n = B * D * H * WG;                 // 245760
    int blocks = (n + 255) / 256;           // 960
    dav_stage2<<<blocks, 256, 0, stream>>>(sn, rq, out);
  }
}